// Round 6
// baseline (597.202 us; speedup 1.0000x reference)
//
#include <hip/hip_runtime.h>

#define DIM 64
#define GPW 4        // 16-row groups per wave in gemm
#define NBSHIFT 8    // bucket = dst >> 8  (256 dsts per bucket)
#define BCAP 3072    // bucket capacity (mean ~1535 for this fixed graph; 2x headroom)

typedef __attribute__((ext_vector_type(8))) __bf16 bf16x8;
typedef __attribute__((ext_vector_type(4))) float f32x4;

__device__ __forceinline__ f32x4 mfma16(bf16x8 a, bf16x8 b, f32x4 c) {
    return __builtin_amdgcn_mfma_f32_16x16x32_bf16(a, b, c, 0, 0, 0);
}

// ---------- CSR build (bucketed two-pass) ----------

__global__ void zero_bcur_kernel(int* __restrict__ bcur, int nb) {
    int i = blockIdx.x * blockDim.x + threadIdx.x;
    if (i < nb) bcur[i] = 0;
}

// pass A: scatter (src,dst) into coarse buckets — appends cluster into hot lines
__global__ void bucket_kernel(const int* __restrict__ ei, int* __restrict__ bcur,
                              int2* __restrict__ buckets, int E_) {
    int e = blockIdx.x * blockDim.x + threadIdx.x;
    if (e >= E_) return;
    int s = ei[e], d = ei[E_ + e];
    int b = d >> NBSHIFT;
    int pos = atomicAdd(&bcur[b], 1);
    if (pos < BCAP) buckets[(size_t)b * BCAP + pos] = make_int2(s, d);
}

// pass B1: per-bucket LDS histogram -> cnt written coalesced (no device atomics)
__global__ __launch_bounds__(256) void hist_kernel(const int* __restrict__ bcur,
                                                   const int2* __restrict__ buckets,
                                                   int* __restrict__ cnt, int n) {
    __shared__ int hist[256];
    hist[threadIdx.x] = 0;
    __syncthreads();
    int b = blockIdx.x;
    int m = min(bcur[b], BCAP);
    int d0 = b << NBSHIFT;
    for (int i = threadIdx.x; i < m; i += 256) {
        int2 e = buckets[(size_t)b * BCAP + i];
        atomicAdd(&hist[e.y - d0], 1);
    }
    __syncthreads();
    int d = d0 + threadIdx.x;
    if (d < n) cnt[d] = hist[threadIdx.x];
}

__global__ __launch_bounds__(256) void scanA_kernel(const int* __restrict__ cnt,
                                                    int* __restrict__ rowptr,
                                                    int* __restrict__ partial, int n) {
    __shared__ int sm[256];
    int tid = threadIdx.x;
    int i = blockIdx.x * 256 + tid;
    int v = (i < n) ? cnt[i] : 0;
    sm[tid] = v;
    __syncthreads();
    for (int off = 1; off < 256; off <<= 1) {
        int t = 0;
        if (tid >= off) t = sm[tid - off];
        __syncthreads();
        if (tid >= off) sm[tid] += t;
        __syncthreads();
    }
    if (i < n) rowptr[i] = sm[tid] - v;
    if (tid == 255) partial[blockIdx.x] = sm[255];
}

__global__ __launch_bounds__(1024) void scanB_kernel(int* __restrict__ partial, int nb) {
    __shared__ int sm[1024];
    int tid = threadIdx.x;
    int v = (tid < nb) ? partial[tid] : 0;
    sm[tid] = v;
    __syncthreads();
    for (int off = 1; off < 1024; off <<= 1) {
        int t = 0;
        if (tid >= off) t = sm[tid - off];
        __syncthreads();
        if (tid >= off) sm[tid] += t;
        __syncthreads();
    }
    if (tid < nb) partial[tid] = sm[tid] - v;
}

__global__ void scanC_kernel(const int* __restrict__ cnt, int* __restrict__ rowptr,
                             float* __restrict__ dinv, const int* __restrict__ partial,
                             int n, int E_) {
    int i = blockIdx.x * blockDim.x + threadIdx.x;
    if (i < n) {
        rowptr[i] += partial[i >> 8];
        dinv[i] = rsqrtf((float)(1 + cnt[i]));
    }
    if (i == 0) rowptr[n] = E_;
}

// pass B2: per-bucket placement with LDS cursors; srcs writes hit a ~6 KB window
__global__ __launch_bounds__(256) void place_kernel(const int* __restrict__ bcur,
                                                    const int2* __restrict__ buckets,
                                                    const int* __restrict__ rowptr,
                                                    int* __restrict__ srcs, int n) {
    __shared__ int lcur[256];
    int b = blockIdx.x;
    int d0 = b << NBSHIFT;
    int d = d0 + threadIdx.x;
    lcur[threadIdx.x] = (d < n) ? rowptr[d] : 0;
    __syncthreads();
    int m = min(bcur[b], BCAP);
    for (int i = threadIdx.x; i < m; i += 256) {
        int2 e = buckets[(size_t)b * BCAP + i];
        int pos = atomicAdd(&lcur[e.y - d0], 1);
        srcs[pos] = e.x;
    }
}

// ---------- layer kernels ----------

// h'(bf16) = (x @ W) * dinv[row].   MFMA 16x16x32 bf16.
template <bool BF16IN>
__global__ __launch_bounds__(256) void gemm_kernel(
    const void* __restrict__ xa_, const void* __restrict__ xb_, int split,
    const float* __restrict__ W, const float* __restrict__ dinv,
    __bf16* __restrict__ h, int n, int ngroups) {
    int lane = threadIdx.x & 63;
    int q = lane >> 4, t = lane & 15;
    int wv = __builtin_amdgcn_readfirstlane(threadIdx.x >> 6);
    int g0 = (blockIdx.x * 4 + wv) * GPW;
    if (g0 >= ngroups) return;

    bf16x8 Bf[4][2];
#pragma unroll
    for (int nt = 0; nt < 4; ++nt)
#pragma unroll
        for (int kt = 0; kt < 2; ++kt) {
            bf16x8 f;
#pragma unroll
            for (int j = 0; j < 8; ++j)
                f[j] = (__bf16)W[(kt * 32 + q * 8 + j) * DIM + nt * 16 + t];
            Bf[nt][kt] = f;
        }

    auto loadA = [&](int r0, f32x4* raw) {
        int row = r0 + t;
        if (row >= n) row = n - 1;
        if constexpr (BF16IN) {
            const __bf16* xr = (const __bf16*)xa_ + (size_t)row * DIM;
            raw[0] = *(const f32x4*)(xr + q * 8);
            raw[1] = *(const f32x4*)(xr + 32 + q * 8);
        } else {
            const float* xr = (row < split)
                ? ((const float*)xa_ + (size_t)row * DIM)
                : ((const float*)xb_ + (size_t)(row - split) * DIM);
            raw[0] = *(const f32x4*)(xr + q * 8);
            raw[1] = *(const f32x4*)(xr + q * 8 + 4);
            raw[2] = *(const f32x4*)(xr + 32 + q * 8);
            raw[3] = *(const f32x4*)(xr + 32 + q * 8 + 4);
        }
    };

    f32x4 cur[4];
    loadA(g0 * 16, cur);

#pragma unroll 1
    for (int gi = 0; gi < GPW; ++gi) {
        int g = g0 + gi;
        if (g >= ngroups) break;
        int r0 = g * 16;
        f32x4 nxt[4];
        bool pf = (gi + 1 < GPW) && (g + 1 < ngroups);
        if (pf) loadA(r0 + 16, nxt);

        bf16x8 A0, A1;
        if constexpr (BF16IN) {
            A0 = __builtin_bit_cast(bf16x8, cur[0]);
            A1 = __builtin_bit_cast(bf16x8, cur[1]);
        } else {
#pragma unroll
            for (int j = 0; j < 4; ++j) {
                A0[j] = (__bf16)cur[0][j]; A0[j + 4] = (__bf16)cur[1][j];
                A1[j] = (__bf16)cur[2][j]; A1[j + 4] = (__bf16)cur[3][j];
            }
        }

        f32x4 z = {0.f, 0.f, 0.f, 0.f};
        f32x4 acc[4];
#pragma unroll
        for (int nt = 0; nt < 4; ++nt)
            acc[nt] = mfma16(A1, Bf[nt][1], mfma16(A0, Bf[nt][0], z));

        f32x4 d4 = *(const f32x4*)(dinv + r0 + q * 4);
#pragma unroll
        for (int nt = 0; nt < 4; ++nt)
#pragma unroll
            for (int reg = 0; reg < 4; ++reg) {
                int row = r0 + q * 4 + reg;
                if (row < n)
                    h[(size_t)row * DIM + nt * 16 + t] =
                        (__bf16)(acc[nt][reg] * d4[reg]);
            }
#pragma unroll
        for (int i = 0; i < 4; ++i) cur[i] = nxt[i];
    }
}

// out[node] = b + dinv[node] * (h'[node] + sum_s h'[s]); unroll-8 gathers
template <typename OutT>
__global__ __launch_bounds__(256) void agg_kernel(
    const int* __restrict__ rowptr, const int* __restrict__ srcs,
    const __bf16* __restrict__ h, const float* __restrict__ bias,
    const float* __restrict__ dinv, OutT* __restrict__ out, int n) {
    int lane = threadIdx.x & 63;
    int node = blockIdx.x * 4 + __builtin_amdgcn_readfirstlane(threadIdx.x >> 6);
    if (node >= n) return;
    int beg = rowptr[node], end = rowptr[node + 1];
    float acc = (float)h[(size_t)node * DIM + lane];   // self-loop row
    float a0 = 0.f, a1 = 0.f, a2 = 0.f, a3 = 0.f;
    int i = beg;
    for (; i + 8 <= end; i += 8) {
        int s0 = srcs[i],     s1 = srcs[i + 1], s2 = srcs[i + 2], s3 = srcs[i + 3];
        int s4 = srcs[i + 4], s5 = srcs[i + 5], s6 = srcs[i + 6], s7 = srcs[i + 7];
        float h0 = (float)h[(size_t)s0 * DIM + lane];
        float h1 = (float)h[(size_t)s1 * DIM + lane];
        float h2 = (float)h[(size_t)s2 * DIM + lane];
        float h3 = (float)h[(size_t)s3 * DIM + lane];
        float h4 = (float)h[(size_t)s4 * DIM + lane];
        float h5 = (float)h[(size_t)s5 * DIM + lane];
        float h6 = (float)h[(size_t)s6 * DIM + lane];
        float h7 = (float)h[(size_t)s7 * DIM + lane];
        a0 += h0 + h4; a1 += h1 + h5; a2 += h2 + h6; a3 += h3 + h7;
    }
    for (; i < end; ++i)
        acc += (float)h[(size_t)srcs[i] * DIM + lane];
    acc += (a0 + a1) + (a2 + a3);
    float res = fmaf(dinv[node], acc, bias[lane]);
    out[(size_t)node * DIM + lane] = (OutT)res;
}

static inline size_t align16(size_t x) { return (x + 15) & ~(size_t)15; }

extern "C" void kernel_launch(void* const* d_in, const int* in_sizes, int n_in,
                              void* d_out, int out_size, void* d_ws, size_t ws_size,
                              hipStream_t stream) {
    const int* ei         = (const int*)d_in[0];
    const float* user_emb = (const float*)d_in[1];
    const float* item_emb = (const float*)d_in[2];
    const float* W1 = (const float*)d_in[3];
    const float* b1 = (const float*)d_in[4];
    const float* W2 = (const float*)d_in[5];
    const float* b2 = (const float*)d_in[6];
    float* out = (float*)d_out;

    const int E_ = in_sizes[0] / 2;
    const int NU = in_sizes[1] / DIM;
    const int NI = in_sizes[2] / DIM;
    const int N_ = NU + NI;
    const int NB = (N_ + 255) >> NBSHIFT;   // buckets of 256 dsts

    // workspace layout (16B-aligned)
    char* p = (char*)d_ws;
    int2* buckets = (int2*)p;                p += align16((size_t)NB * BCAP * 8);
    int* srcs = (int*)p;                     p += align16((size_t)E_ * 4);
    __bf16* h  = (__bf16*)p;                 p += align16((size_t)N_ * DIM * 2);
    __bf16* t1 = (__bf16*)p;                 p += align16((size_t)N_ * DIM * 2);
    float* dinv = (float*)p;                 p += align16((size_t)N_ * 4);
    int* cnt    = (int*)p;                   p += align16((size_t)N_ * 4);
    int* rowptr = (int*)p;                   p += align16((size_t)(N_ + 1) * 4);
    int* bcur   = (int*)p;                   p += align16((size_t)NB * 4);
    int* partial = (int*)p;                  p += align16(1024 * 4);

    int nb256 = (N_ + 255) / 256;

    zero_bcur_kernel<<<(NB + 1023) / 1024, 1024, 0, stream>>>(bcur, NB);
    bucket_kernel<<<(E_ + 255) / 256, 256, 0, stream>>>(ei, bcur, buckets, E_);
    hist_kernel<<<NB, 256, 0, stream>>>(bcur, buckets, cnt, N_);
    scanA_kernel<<<nb256, 256, 0, stream>>>(cnt, rowptr, partial, N_);
    scanB_kernel<<<1, 1024, 0, stream>>>(partial, nb256);
    scanC_kernel<<<(N_ + 255) / 256, 256, 0, stream>>>(cnt, rowptr, dinv,
                                                       partial, N_, E_);
    place_kernel<<<NB, 256, 0, stream>>>(bcur, buckets, rowptr, srcs, N_);

    int NG = (N_ + 15) / 16;
    int gblocks = (NG + 4 * GPW - 1) / (4 * GPW);
    int ablocks = (N_ + 3) / 4;

    // layer 1
    gemm_kernel<false><<<gblocks, 256, 0, stream>>>(user_emb, item_emb, NU,
                                                    W1, dinv, h, N_, NG);
    agg_kernel<__bf16><<<ablocks, 256, 0, stream>>>(rowptr, srcs, h, b1, dinv, t1, N_);
    // layer 2
    gemm_kernel<true><<<gblocks, 256, 0, stream>>>(t1, t1, N_,
                                                   W2, dinv, h, N_, NG);
    agg_kernel<float><<<ablocks, 256, 0, stream>>>(rowptr, srcs, h, b2, dinv, out, N_);
}

// Round 7
// 417.890 us; speedup vs baseline: 1.4291x; 1.4291x over previous
//
#include <hip/hip_runtime.h>

#define DIM 64
#define GPW 4       // 16-row groups per wave in gemm
#define WSHIFT 15   // dst-window = dst >> 15 (32768 dsts per window)

typedef __attribute__((ext_vector_type(8))) __bf16 bf16x8;
typedef __attribute__((ext_vector_type(4))) float f32x4;

__device__ __forceinline__ f32x4 mfma16(bf16x8 a, bf16x8 b, f32x4 c) {
    return __builtin_amdgcn_mfma_f32_16x16x32_bf16(a, b, c, 0, 0, 0);
}

// ---------- CSR build ----------

__global__ void zero_cnt_kernel(int* __restrict__ cnt, int n) {
    int i = blockIdx.x * blockDim.x + threadIdx.x;
    if (i < n) cnt[i] = 0;
}

// dst-windowed count: active cnt window ~128 KB stays L2-resident
__global__ __launch_bounds__(256) void count_kernel(const int* __restrict__ ei,
                                                    int* __restrict__ cnt,
                                                    int E_, int nw) {
    int e = blockIdx.x * blockDim.x + threadIdx.x;
    bool valid = e < E_;
    int d = valid ? ei[E_ + e] : 0;
    int w = d >> WSHIFT;
    for (int p = 0; p < nw; ++p) {
        if (valid && w == p) atomicAdd(&cnt[d], 1);
        __syncthreads();   // soft lockstep between windows
    }
}

__global__ __launch_bounds__(256) void scanA_kernel(const int* __restrict__ cnt,
                                                    int* __restrict__ rowptr,
                                                    int* __restrict__ partial, int n) {
    __shared__ int sm[256];
    int tid = threadIdx.x;
    int i = blockIdx.x * 256 + tid;
    int v = (i < n) ? cnt[i] : 0;
    sm[tid] = v;
    __syncthreads();
    for (int off = 1; off < 256; off <<= 1) {
        int t = 0;
        if (tid >= off) t = sm[tid - off];
        __syncthreads();
        if (tid >= off) sm[tid] += t;
        __syncthreads();
    }
    if (i < n) rowptr[i] = sm[tid] - v;
    if (tid == 255) partial[blockIdx.x] = sm[255];
}

__global__ __launch_bounds__(1024) void scanB_kernel(int* __restrict__ partial, int nb) {
    __shared__ int sm[1024];
    int tid = threadIdx.x;
    int v = (tid < nb) ? partial[tid] : 0;
    sm[tid] = v;
    __syncthreads();
    for (int off = 1; off < 1024; off <<= 1) {
        int t = 0;
        if (tid >= off) t = sm[tid - off];
        __syncthreads();
        if (tid >= off) sm[tid] += t;
        __syncthreads();
    }
    if (tid < nb) partial[tid] = sm[tid] - v;
}

__global__ void scanC_kernel(const int* __restrict__ cnt, int* __restrict__ rowptr,
                             int* __restrict__ cursor, float* __restrict__ dinv,
                             const int* __restrict__ partial, int n, int E_) {
    int i = blockIdx.x * blockDim.x + threadIdx.x;
    if (i < n) {
        int val = rowptr[i] + partial[i >> 8];
        rowptr[i] = val;
        cursor[i] = val;
        dinv[i] = rsqrtf((float)(1 + cnt[i]));
    }
    if (i == 0) rowptr[n] = E_;
}

// dst-windowed CSR fill: active srcs window ~686 KB, cursor window ~128 KB
__global__ __launch_bounds__(256) void fill_kernel(const int* __restrict__ ei,
                                                   int* __restrict__ cursor,
                                                   int* __restrict__ srcs,
                                                   int E_, int nw) {
    int e = blockIdx.x * blockDim.x + threadIdx.x;
    bool valid = e < E_;
    int s = valid ? ei[e] : 0;
    int d = valid ? ei[E_ + e] : 0;
    int w = d >> WSHIFT;
    for (int p = 0; p < nw; ++p) {
        if (valid && w == p) {
            int pos = atomicAdd(&cursor[d], 1);
            srcs[pos] = s;
        }
        __syncthreads();   // soft lockstep between windows
    }
}

// ---------- layer kernels ----------

// h'(bf16) = (x @ W) * dinv[row].   MFMA 16x16x32 bf16.
template <bool BF16IN>
__global__ __launch_bounds__(256) void gemm_kernel(
    const void* __restrict__ xa_, const void* __restrict__ xb_, int split,
    const float* __restrict__ W, const float* __restrict__ dinv,
    __bf16* __restrict__ h, int n, int ngroups) {
    int lane = threadIdx.x & 63;
    int q = lane >> 4, t = lane & 15;
    int wv = __builtin_amdgcn_readfirstlane(threadIdx.x >> 6);
    int g0 = (blockIdx.x * 4 + wv) * GPW;
    if (g0 >= ngroups) return;

    bf16x8 Bf[4][2];
#pragma unroll
    for (int nt = 0; nt < 4; ++nt)
#pragma unroll
        for (int kt = 0; kt < 2; ++kt) {
            bf16x8 f;
#pragma unroll
            for (int j = 0; j < 8; ++j)
                f[j] = (__bf16)W[(kt * 32 + q * 8 + j) * DIM + nt * 16 + t];
            Bf[nt][kt] = f;
        }

    auto loadA = [&](int r0, f32x4* raw) {
        int row = r0 + t;
        if (row >= n) row = n - 1;
        if constexpr (BF16IN) {
            const __bf16* xr = (const __bf16*)xa_ + (size_t)row * DIM;
            raw[0] = *(const f32x4*)(xr + q * 8);
            raw[1] = *(const f32x4*)(xr + 32 + q * 8);
        } else {
            const float* xr = (row < split)
                ? ((const float*)xa_ + (size_t)row * DIM)
                : ((const float*)xb_ + (size_t)(row - split) * DIM);
            raw[0] = *(const f32x4*)(xr + q * 8);
            raw[1] = *(const f32x4*)(xr + q * 8 + 4);
            raw[2] = *(const f32x4*)(xr + 32 + q * 8);
            raw[3] = *(const f32x4*)(xr + 32 + q * 8 + 4);
        }
    };

    f32x4 cur[4];
    loadA(g0 * 16, cur);

#pragma unroll 1
    for (int gi = 0; gi < GPW; ++gi) {
        int g = g0 + gi;
        if (g >= ngroups) break;
        int r0 = g * 16;
        f32x4 nxt[4];
        bool pf = (gi + 1 < GPW) && (g + 1 < ngroups);
        if (pf) loadA(r0 + 16, nxt);

        bf16x8 A0, A1;
        if constexpr (BF16IN) {
            A0 = __builtin_bit_cast(bf16x8, cur[0]);
            A1 = __builtin_bit_cast(bf16x8, cur[1]);
        } else {
#pragma unroll
            for (int j = 0; j < 4; ++j) {
                A0[j] = (__bf16)cur[0][j]; A0[j + 4] = (__bf16)cur[1][j];
                A1[j] = (__bf16)cur[2][j]; A1[j + 4] = (__bf16)cur[3][j];
            }
        }

        f32x4 z = {0.f, 0.f, 0.f, 0.f};
        f32x4 acc[4];
#pragma unroll
        for (int nt = 0; nt < 4; ++nt)
            acc[nt] = mfma16(A1, Bf[nt][1], mfma16(A0, Bf[nt][0], z));

        f32x4 d4 = *(const f32x4*)(dinv + r0 + q * 4);
#pragma unroll
        for (int nt = 0; nt < 4; ++nt)
#pragma unroll
            for (int reg = 0; reg < 4; ++reg) {
                int row = r0 + q * 4 + reg;
                if (row < n)
                    h[(size_t)row * DIM + nt * 16 + t] =
                        (__bf16)(acc[nt][reg] * d4[reg]);
            }
#pragma unroll
        for (int i = 0; i < 4; ++i) cur[i] = nxt[i];
    }
}

// out[node] = b + dinv[node] * (h'[node] + sum_s h'[s]); unroll-8 gathers
template <typename OutT>
__global__ __launch_bounds__(256) void agg_kernel(
    const int* __restrict__ rowptr, const int* __restrict__ srcs,
    const __bf16* __restrict__ h, const float* __restrict__ bias,
    const float* __restrict__ dinv, OutT* __restrict__ out, int n) {
    int lane = threadIdx.x & 63;
    int node = blockIdx.x * 4 + __builtin_amdgcn_readfirstlane(threadIdx.x >> 6);
    if (node >= n) return;
    int beg = rowptr[node], end = rowptr[node + 1];
    float acc = (float)h[(size_t)node * DIM + lane];   // self-loop row
    float a0 = 0.f, a1 = 0.f, a2 = 0.f, a3 = 0.f;
    int i = beg;
    for (; i + 8 <= end; i += 8) {
        int s0 = srcs[i],     s1 = srcs[i + 1], s2 = srcs[i + 2], s3 = srcs[i + 3];
        int s4 = srcs[i + 4], s5 = srcs[i + 5], s6 = srcs[i + 6], s7 = srcs[i + 7];
        float h0 = (float)h[(size_t)s0 * DIM + lane];
        float h1 = (float)h[(size_t)s1 * DIM + lane];
        float h2 = (float)h[(size_t)s2 * DIM + lane];
        float h3 = (float)h[(size_t)s3 * DIM + lane];
        float h4 = (float)h[(size_t)s4 * DIM + lane];
        float h5 = (float)h[(size_t)s5 * DIM + lane];
        float h6 = (float)h[(size_t)s6 * DIM + lane];
        float h7 = (float)h[(size_t)s7 * DIM + lane];
        a0 += h0 + h4; a1 += h1 + h5; a2 += h2 + h6; a3 += h3 + h7;
    }
    for (; i < end; ++i)
        acc += (float)h[(size_t)srcs[i] * DIM + lane];
    acc += (a0 + a1) + (a2 + a3);
    float res = fmaf(dinv[node], acc, bias[lane]);
    out[(size_t)node * DIM + lane] = (OutT)res;
}

static inline size_t align16(size_t x) { return (x + 15) & ~(size_t)15; }

extern "C" void kernel_launch(void* const* d_in, const int* in_sizes, int n_in,
                              void* d_out, int out_size, void* d_ws, size_t ws_size,
                              hipStream_t stream) {
    const int* ei         = (const int*)d_in[0];
    const float* user_emb = (const float*)d_in[1];
    const float* item_emb = (const float*)d_in[2];
    const float* W1 = (const float*)d_in[3];
    const float* b1 = (const float*)d_in[4];
    const float* W2 = (const float*)d_in[5];
    const float* b2 = (const float*)d_in[6];
    float* out = (float*)d_out;

    const int E_ = in_sizes[0] / 2;
    const int NU = in_sizes[1] / DIM;
    const int NI = in_sizes[2] / DIM;
    const int N_ = NU + NI;
    const int NW = (N_ + (1 << WSHIFT) - 1) >> WSHIFT;   // dst windows

    // workspace layout (16B-aligned)
    char* p = (char*)d_ws;
    int* srcs = (int*)p;                     p += align16((size_t)E_ * 4);
    __bf16* h  = (__bf16*)p;                 p += align16((size_t)N_ * DIM * 2);
    __bf16* t1 = (__bf16*)p;                 p += align16((size_t)N_ * DIM * 2);
    float* dinv = (float*)p;                 p += align16((size_t)N_ * 4);
    int* cnt    = (int*)p;                   p += align16((size_t)N_ * 4);
    int* rowptr = (int*)p;                   p += align16((size_t)(N_ + 1) * 4);
    int* cursor = (int*)p;                   p += align16((size_t)N_ * 4);
    int* partial = (int*)p;                  p += align16(1024 * 4);

    int nb256 = (N_ + 255) / 256;
    int eblocks = (E_ + 255) / 256;

    zero_cnt_kernel<<<nb256, 256, 0, stream>>>(cnt, N_);
    count_kernel<<<eblocks, 256, 0, stream>>>(ei, cnt, E_, NW);
    scanA_kernel<<<nb256, 256, 0, stream>>>(cnt, rowptr, partial, N_);
    scanB_kernel<<<1, 1024, 0, stream>>>(partial, nb256);
    scanC_kernel<<<nb256, 256, 0, stream>>>(cnt, rowptr, cursor, dinv,
                                            partial, N_, E_);
    fill_kernel<<<eblocks, 256, 0, stream>>>(ei, cursor, srcs, E_, NW);

    int NG = (N_ + 15) / 16;
    int gblocks = (NG + 4 * GPW - 1) / (4 * GPW);
    int ablocks = (N_ + 3) / 4;

    // layer 1
    gemm_kernel<false><<<gblocks, 256, 0, stream>>>(user_emb, item_emb, NU,
                                                    W1, dinv, h, N_, NG);
    agg_kernel<__bf16><<<ablocks, 256, 0, stream>>>(rowptr, srcs, h, b1, dinv, t1, N_);
    // layer 2
    gemm_kernel<true><<<gblocks, 256, 0, stream>>>(t1, t1, N_,
                                                   W2, dinv, h, N_, NG);
    agg_kernel<float><<<ablocks, 256, 0, stream>>>(rowptr, srcs, h, b2, dinv, out, N_);
}